// Round 11
// baseline (168.861 us; speedup 1.0000x reference)
//
#include <hip/hip_runtime.h>

// SpatialEngram: out[b,o,i,j] = (table @ proj_w.T + proj_b)[idx[b,i,j]][o]
// where idx = trunc(mean_c(abs(3x3_sum(trunc(x*100)))%P))
//
// Round 11: MEASUREMENT ROUND. Pipeline identical to Round 10 (112.8 us),
// but expand3_kernel is launched TWICE (idempotent rewrite of the same
// bytes). T_expand = total - 112.8; T_idx ~= 112.8 - T_expand - ~5 (proj).
// Duplicating expand (not idx) because the write stream has no cache-warmth
// contamination. This resolves the phase split that 5 rounds of structure
// A/Bs (all landing 108-113 us) could not.

#define CH  32
#define HH  512
#define WW  512
#define EE  64
#define OUT 64
#define PP  10000

#define TWPX 256              // idx kernel: tile width in px (64 thr x 4 px)
#define HW   (HH * WW)        // 262144 = 2^18

typedef float f32x4 __attribute__((ext_vector_type(4)));

__global__ __launch_bounds__(256) void proj_kernel(
    const float* __restrict__ table, const float* __restrict__ pw,
    const float* __restrict__ pb, float* __restrict__ tpT) {
  __shared__ float sW[EE * OUT];          // sW[e*64 + o] = pw[o*64 + e]
  const int t = threadIdx.x;              // 0..255
  for (int i = t; i < EE * OUT; i += 256) {
    int o = i >> 6, e = i & 63;
    sW[e * OUT + o] = pw[i];
  }
  __syncthreads();
  const int o  = t & 63;
  const int pr = t >> 6;                  // 0..3
  const int p0 = blockIdx.x * 16 + pr;    // rows p0, p0+4, p0+8, p0+12
  const float4* r0 = (const float4*)(table + (size_t)(p0     ) * EE);
  const float4* r1 = (const float4*)(table + (size_t)(p0 +  4) * EE);
  const float4* r2 = (const float4*)(table + (size_t)(p0 +  8) * EE);
  const float4* r3 = (const float4*)(table + (size_t)(p0 + 12) * EE);
  float a0 = pb[o], a1 = pb[o], a2 = pb[o], a3 = pb[o];
  float b0 = 0.f,  b1 = 0.f,  b2 = 0.f,  b3 = 0.f;
  #pragma unroll
  for (int e4 = 0; e4 < EE / 4; ++e4) {
    float4 t0 = r0[e4], t1 = r1[e4], t2 = r2[e4], t3 = r3[e4];
    float w0 = sW[(4 * e4 + 0) * OUT + o];
    float w1 = sW[(4 * e4 + 1) * OUT + o];
    float w2 = sW[(4 * e4 + 2) * OUT + o];
    float w3 = sW[(4 * e4 + 3) * OUT + o];
    a0 = fmaf(t0.x, w0, a0); b0 = fmaf(t0.y, w1, b0);
    a0 = fmaf(t0.z, w2, a0); b0 = fmaf(t0.w, w3, b0);
    a1 = fmaf(t1.x, w0, a1); b1 = fmaf(t1.y, w1, b1);
    a1 = fmaf(t1.z, w2, a1); b1 = fmaf(t1.w, w3, b1);
    a2 = fmaf(t2.x, w0, a2); b2 = fmaf(t2.y, w1, b2);
    a2 = fmaf(t2.z, w2, a2); b2 = fmaf(t2.w, w3, b2);
    a3 = fmaf(t3.x, w0, a3); b3 = fmaf(t3.y, w1, b3);
    a3 = fmaf(t3.z, w2, a3); b3 = fmaf(t3.w, w3, b3);
  }
  float* oc = tpT + (size_t)o * PP;
  oc[p0]      = a0 + b0;
  oc[p0 + 4]  = a1 + b1;
  oc[p0 + 8]  = a2 + b2;
  oc[p0 + 12] = a3 + b3;
}

__device__ __forceinline__ int q3(float a, float b, float c) {
  // column sum of trunc(v*100) over 3 rows; (int) truncates toward zero
  return (int)(a * 100.0f) + (int)(b * 100.0f) + (int)(c * 100.0f);
}

__global__ __launch_bounds__(256) void idx_kernel(
    const float* __restrict__ x, unsigned short* __restrict__ idx16) {
  const int tx  = threadIdx.x;            // 0..63
  const int ty  = threadIdx.y;            // 0..3
  const int gx0 = blockIdx.x * TWPX;
  const int y   = blockIdx.y * 4 + ty;
  const int b   = blockIdx.z;
  const int x0  = gx0 + tx * 4;

  const int ym1 = max(y - 1, 0);
  const int yp1 = min(y + 1, HH - 1);
  const size_t rm1 = (size_t)ym1 * WW + x0;
  const size_t r0  = (size_t)y   * WW + x0;
  const size_t rp1 = (size_t)yp1 * WW + x0;

  const bool edge = (tx == 0) || (tx == 63);
  const int  ecol = (tx == 0) ? max(gx0 - 1, 0) : min(gx0 + TWPX, WW - 1);
  const size_t em1 = (size_t)ym1 * WW + ecol;
  const size_t e0  = (size_t)y   * WW + ecol;
  const size_t ep1 = (size_t)yp1 * WW + ecol;

  const float* xb = x + (size_t)b * CH * HW;

  int acc0 = 0, acc1 = 0, acc2 = 0, acc3 = 0;
  #pragma unroll 2
  for (int c = 0; c < CH; ++c) {
    const float* xc = xb + (size_t)c * HW;
    float4 a = *(const float4*)(xc + rm1);
    float4 m = *(const float4*)(xc + r0);
    float4 p = *(const float4*)(xc + rp1);

    int cs0 = q3(a.x, m.x, p.x);
    int cs1 = q3(a.y, m.y, p.y);
    int cs2 = q3(a.z, m.z, p.z);
    int cs3 = q3(a.w, m.w, p.w);

    int csl = __shfl(cs3, tx - 1, 64);    // junk for tx==0 (overwritten)
    int csr = __shfl(cs0, tx + 1, 64);    // junk for tx==63 (overwritten)
    if (edge) {
      int e = q3(xc[em1], xc[e0], xc[ep1]);
      if (tx == 0) csl = e; else csr = e;
    }

    int h0 = csl + cs0 + cs1;
    int h1 = cs0 + cs1 + cs2;
    int h2 = cs1 + cs2 + cs3;
    int h3 = cs2 + cs3 + csr;

    acc0 += (int)((unsigned)(h0 < 0 ? -h0 : h0) % PP);
    acc1 += (int)((unsigned)(h1 < 0 ? -h1 : h1) % PP);
    acc2 += (int)((unsigned)(h2 < 0 ? -h2 : h2) % PP);
    acc3 += (int)((unsigned)(h3 < 0 ? -h3 : h3) % PP);
  }
  // mean over 32 channels, exact in f32; trunc of nonneg == >>5
  const unsigned i0 = (unsigned)(acc0 >> 5), i1 = (unsigned)(acc1 >> 5);
  const unsigned i2 = (unsigned)(acc2 >> 5), i3 = (unsigned)(acc3 >> 5);

  const size_t pix = (size_t)b * HW + (size_t)y * WW + x0;
  uint2 pk = make_uint2(i0 | (i1 << 16), i2 | (i3 << 16));
  *(uint2*)(idx16 + pix) = pk;
}

__global__ __launch_bounds__(256) void expand3_kernel(
    const unsigned short* __restrict__ idx16, const float* __restrict__ tpT,
    float* __restrict__ out) {
  const int t = threadIdx.x;
  const unsigned bid   = blockIdx.x;             // b*2048 + o*32 + chunk
  const int      chunk = bid & 31;               // 32 chunks x 16 rows
  const int      o     = (bid >> 5) & 63;
  const int      b     = bid >> 11;

  const float* col = tpT + (size_t)o * PP;       // hot band <1KB -> L1
  const size_t pixbase = (size_t)chunk * 8192;   // 16 rows
  const unsigned short* ip = idx16 + (size_t)b * HW + pixbase;
  float* op = out + ((size_t)b * OUT + o) * HW + pixbase;

  // batch all 8 idx loads up front (independent), then gather+store pipelined
  uint2 pk0 = *(const uint2*)(ip + 0 * 1024 + t * 4);
  uint2 pk1 = *(const uint2*)(ip + 1 * 1024 + t * 4);
  uint2 pk2 = *(const uint2*)(ip + 2 * 1024 + t * 4);
  uint2 pk3 = *(const uint2*)(ip + 3 * 1024 + t * 4);
  uint2 pk4 = *(const uint2*)(ip + 4 * 1024 + t * 4);
  uint2 pk5 = *(const uint2*)(ip + 5 * 1024 + t * 4);
  uint2 pk6 = *(const uint2*)(ip + 6 * 1024 + t * 4);
  uint2 pk7 = *(const uint2*)(ip + 7 * 1024 + t * 4);

#define EXPAND_ONE(pk, j)                                                  \
  {                                                                        \
    const unsigned i0 = pk.x & 0xFFFFu, i1 = pk.x >> 16;                   \
    const unsigned i2 = pk.y & 0xFFFFu, i3 = pk.y >> 16;                   \
    f32x4 v = { col[i0], col[i1], col[i2], col[i3] };                      \
    __builtin_nontemporal_store(v, (f32x4*)(op + (j) * 1024 + t * 4));     \
  }

  EXPAND_ONE(pk0, 0)
  EXPAND_ONE(pk1, 1)
  EXPAND_ONE(pk2, 2)
  EXPAND_ONE(pk3, 3)
  EXPAND_ONE(pk4, 4)
  EXPAND_ONE(pk5, 5)
  EXPAND_ONE(pk6, 6)
  EXPAND_ONE(pk7, 7)
#undef EXPAND_ONE
}

extern "C" void kernel_launch(void* const* d_in, const int* in_sizes, int n_in,
                              void* d_out, int out_size, void* d_ws, size_t ws_size,
                              hipStream_t stream) {
  const float* x     = (const float*)d_in[0];  // (4,32,512,512)
  const float* table = (const float*)d_in[1];  // (10000,64)
  const float* pw    = (const float*)d_in[2];  // (64,64)
  const float* pb    = (const float*)d_in[3];  // (64,)
  float* out = (float*)d_out;                  // (4,64,512,512)

  const int B = in_sizes[0] / (CH * HW);       // 4

  float* tpT = (float*)d_ws;                                        // 2.56 MB
  unsigned short* idx16 =
      (unsigned short*)((char*)d_ws + (size_t)OUT * PP * 4);        // 2 MB

  proj_kernel<<<PP / 16, 256, 0, stream>>>(table, pw, pb, tpT);

  dim3 block(64, 4, 1);
  dim3 grid(WW / TWPX, HH / 4, B);             // (2, 128, 4)
  idx_kernel<<<grid, block, 0, stream>>>(x, idx16);

  const int nblk = B * OUT * 32;               // 8192 blocks, 16 rows each
  expand3_kernel<<<nblk, 256, 0, stream>>>(idx16, tpT, out);
  // MEASUREMENT: duplicate expand dispatch (idempotent rewrite).
  // T_expand = total_dur - 112.8us (Round 10 baseline).
  expand3_kernel<<<nblk, 256, 0, stream>>>(idx16, tpT, out);
}

// Round 12
// 116.424 us; speedup vs baseline: 1.4504x; 1.4504x over previous
//
#include <hip/hip_runtime.h>

// SpatialEngram: out[b,o,i,j] = (table @ proj_w.T + proj_b)[idx[b,i,j]][o]
// where idx = trunc(mean_c(abs(3x3_sum(trunc(x*100)))%P))
//
// Round 12: measurement (R11) convicted idx (~50us vs 21us floor; expand
// ~52-56us ~ its mixed gather+write ceiling). idx is TLP-starved: 4 px/thread
// -> 4096 waves total = 16 waves/CU = 4/SIMD; ~6 loads in flight per wave
// can't cover ~900cy HBM latency. ONE change: 2 px/thread (TWPX 128, float2
// loads) -> 8192 waves = 32/CU = 8/SIMD. proj/expand identical to R10.

#define CH  32
#define HH  512
#define WW  512
#define EE  64
#define OUT 64
#define PP  10000

#define TWPX 128              // idx kernel: tile width in px (64 thr x 2 px)
#define HW   (HH * WW)        // 262144 = 2^18

typedef float f32x4 __attribute__((ext_vector_type(4)));

__global__ __launch_bounds__(256) void proj_kernel(
    const float* __restrict__ table, const float* __restrict__ pw,
    const float* __restrict__ pb, float* __restrict__ tpT) {
  __shared__ float sW[EE * OUT];          // sW[e*64 + o] = pw[o*64 + e]
  const int t = threadIdx.x;              // 0..255
  for (int i = t; i < EE * OUT; i += 256) {
    int o = i >> 6, e = i & 63;
    sW[e * OUT + o] = pw[i];
  }
  __syncthreads();
  const int o  = t & 63;
  const int pr = t >> 6;                  // 0..3
  const int p0 = blockIdx.x * 16 + pr;    // rows p0, p0+4, p0+8, p0+12
  const float4* r0 = (const float4*)(table + (size_t)(p0     ) * EE);
  const float4* r1 = (const float4*)(table + (size_t)(p0 +  4) * EE);
  const float4* r2 = (const float4*)(table + (size_t)(p0 +  8) * EE);
  const float4* r3 = (const float4*)(table + (size_t)(p0 + 12) * EE);
  float a0 = pb[o], a1 = pb[o], a2 = pb[o], a3 = pb[o];
  float b0 = 0.f,  b1 = 0.f,  b2 = 0.f,  b3 = 0.f;
  #pragma unroll
  for (int e4 = 0; e4 < EE / 4; ++e4) {
    float4 t0 = r0[e4], t1 = r1[e4], t2 = r2[e4], t3 = r3[e4];
    float w0 = sW[(4 * e4 + 0) * OUT + o];
    float w1 = sW[(4 * e4 + 1) * OUT + o];
    float w2 = sW[(4 * e4 + 2) * OUT + o];
    float w3 = sW[(4 * e4 + 3) * OUT + o];
    a0 = fmaf(t0.x, w0, a0); b0 = fmaf(t0.y, w1, b0);
    a0 = fmaf(t0.z, w2, a0); b0 = fmaf(t0.w, w3, b0);
    a1 = fmaf(t1.x, w0, a1); b1 = fmaf(t1.y, w1, b1);
    a1 = fmaf(t1.z, w2, a1); b1 = fmaf(t1.w, w3, b1);
    a2 = fmaf(t2.x, w0, a2); b2 = fmaf(t2.y, w1, b2);
    a2 = fmaf(t2.z, w2, a2); b2 = fmaf(t2.w, w3, b2);
    a3 = fmaf(t3.x, w0, a3); b3 = fmaf(t3.y, w1, b3);
    a3 = fmaf(t3.z, w2, a3); b3 = fmaf(t3.w, w3, b3);
  }
  float* oc = tpT + (size_t)o * PP;
  oc[p0]      = a0 + b0;
  oc[p0 + 4]  = a1 + b1;
  oc[p0 + 8]  = a2 + b2;
  oc[p0 + 12] = a3 + b3;
}

__device__ __forceinline__ int q3(float a, float b, float c) {
  // column sum of trunc(v*100) over 3 rows; (int) truncates toward zero
  return (int)(a * 100.0f) + (int)(b * 100.0f) + (int)(c * 100.0f);
}

__global__ __launch_bounds__(256) void idx_kernel(
    const float* __restrict__ x, unsigned short* __restrict__ idx16) {
  const int tx  = threadIdx.x;            // 0..63
  const int ty  = threadIdx.y;            // 0..3
  const int gx0 = blockIdx.x * TWPX;
  const int y   = blockIdx.y * 4 + ty;
  const int b   = blockIdx.z;
  const int x0  = gx0 + tx * 2;           // 2 px per thread

  const int ym1 = max(y - 1, 0);
  const int yp1 = min(y + 1, HH - 1);
  const size_t rm1 = (size_t)ym1 * WW + x0;
  const size_t r0  = (size_t)y   * WW + x0;
  const size_t rp1 = (size_t)yp1 * WW + x0;

  const bool edge = (tx == 0) || (tx == 63);
  const int  ecol = (tx == 0) ? max(gx0 - 1, 0) : min(gx0 + TWPX, WW - 1);
  const size_t em1 = (size_t)ym1 * WW + ecol;
  const size_t e0  = (size_t)y   * WW + ecol;
  const size_t ep1 = (size_t)yp1 * WW + ecol;

  const float* xb = x + (size_t)b * CH * HW;

  int acc0 = 0, acc1 = 0;
  #pragma unroll 2
  for (int c = 0; c < CH; ++c) {
    const float* xc = xb + (size_t)c * HW;
    float2 a = *(const float2*)(xc + rm1);
    float2 m = *(const float2*)(xc + r0);
    float2 p = *(const float2*)(xc + rp1);

    int cs0 = q3(a.x, m.x, p.x);
    int cs1 = q3(a.y, m.y, p.y);

    int csl = __shfl(cs1, tx - 1, 64);    // junk for tx==0 (overwritten)
    int csr = __shfl(cs0, tx + 1, 64);    // junk for tx==63 (overwritten)
    if (edge) {
      int e = q3(xc[em1], xc[e0], xc[ep1]);
      if (tx == 0) csl = e; else csr = e;
    }

    int h0 = csl + cs0 + cs1;
    int h1 = cs0 + cs1 + csr;

    acc0 += (int)((unsigned)(h0 < 0 ? -h0 : h0) % PP);
    acc1 += (int)((unsigned)(h1 < 0 ? -h1 : h1) % PP);
  }
  // mean over 32 channels, exact in f32; trunc of nonneg == >>5
  const unsigned i0 = (unsigned)(acc0 >> 5), i1 = (unsigned)(acc1 >> 5);

  const size_t pix = (size_t)b * HW + (size_t)y * WW + x0;
  *(unsigned*)(idx16 + pix) = i0 | (i1 << 16);
}

__global__ __launch_bounds__(256) void expand3_kernel(
    const unsigned short* __restrict__ idx16, const float* __restrict__ tpT,
    float* __restrict__ out) {
  const int t = threadIdx.x;
  const unsigned bid   = blockIdx.x;             // b*2048 + o*32 + chunk
  const int      chunk = bid & 31;               // 32 chunks x 16 rows
  const int      o     = (bid >> 5) & 63;
  const int      b     = bid >> 11;

  const float* col = tpT + (size_t)o * PP;       // hot band <1KB -> L1
  const size_t pixbase = (size_t)chunk * 8192;   // 16 rows
  const unsigned short* ip = idx16 + (size_t)b * HW + pixbase;
  float* op = out + ((size_t)b * OUT + o) * HW + pixbase;

  // batch all 8 idx loads up front (independent), then gather+store pipelined
  uint2 pk0 = *(const uint2*)(ip + 0 * 1024 + t * 4);
  uint2 pk1 = *(const uint2*)(ip + 1 * 1024 + t * 4);
  uint2 pk2 = *(const uint2*)(ip + 2 * 1024 + t * 4);
  uint2 pk3 = *(const uint2*)(ip + 3 * 1024 + t * 4);
  uint2 pk4 = *(const uint2*)(ip + 4 * 1024 + t * 4);
  uint2 pk5 = *(const uint2*)(ip + 5 * 1024 + t * 4);
  uint2 pk6 = *(const uint2*)(ip + 6 * 1024 + t * 4);
  uint2 pk7 = *(const uint2*)(ip + 7 * 1024 + t * 4);

#define EXPAND_ONE(pk, j)                                                  \
  {                                                                        \
    const unsigned i0 = pk.x & 0xFFFFu, i1 = pk.x >> 16;                   \
    const unsigned i2 = pk.y & 0xFFFFu, i3 = pk.y >> 16;                   \
    f32x4 v = { col[i0], col[i1], col[i2], col[i3] };                      \
    __builtin_nontemporal_store(v, (f32x4*)(op + (j) * 1024 + t * 4));     \
  }

  EXPAND_ONE(pk0, 0)
  EXPAND_ONE(pk1, 1)
  EXPAND_ONE(pk2, 2)
  EXPAND_ONE(pk3, 3)
  EXPAND_ONE(pk4, 4)
  EXPAND_ONE(pk5, 5)
  EXPAND_ONE(pk6, 6)
  EXPAND_ONE(pk7, 7)
#undef EXPAND_ONE
}

extern "C" void kernel_launch(void* const* d_in, const int* in_sizes, int n_in,
                              void* d_out, int out_size, void* d_ws, size_t ws_size,
                              hipStream_t stream) {
  const float* x     = (const float*)d_in[0];  // (4,32,512,512)
  const float* table = (const float*)d_in[1];  // (10000,64)
  const float* pw    = (const float*)d_in[2];  // (64,64)
  const float* pb    = (const float*)d_in[3];  // (64,)
  float* out = (float*)d_out;                  // (4,64,512,512)

  const int B = in_sizes[0] / (CH * HW);       // 4

  float* tpT = (float*)d_ws;                                        // 2.56 MB
  unsigned short* idx16 =
      (unsigned short*)((char*)d_ws + (size_t)OUT * PP * 4);        // 2 MB

  proj_kernel<<<PP / 16, 256, 0, stream>>>(table, pw, pb, tpT);

  dim3 block(64, 4, 1);
  dim3 grid(WW / TWPX, HH / 4, B);             // (4, 128, 4) = 2048 blocks
  idx_kernel<<<grid, block, 0, stream>>>(x, idx16);

  const int nblk = B * OUT * 32;               // 8192 blocks, 16 rows each
  expand3_kernel<<<nblk, 256, 0, stream>>>(idx16, tpT, out);
}

// Round 13
// 110.854 us; speedup vs baseline: 1.5233x; 1.0502x over previous
//
#include <hip/hip_runtime.h>

// SpatialEngram: out[b,o,i,j] = (table @ proj_w.T + proj_b)[idx[b,i,j]][o]
// where idx = trunc(mean_c(abs(3x3_sum(trunc(x*100)))%P))
//
// Round 13: idx rebuilt as FULL-ROW waves (contiguous-stream theory).
//   Evidence: R12 (smaller chunks, 2x waves) slightly worse; R3->R4 jump
//   coincided with 256B->1KB chunks; fills (long sequential) hit 7 TB/s,
//   expand (128KB regions) ~5 TB/s, idx (1-2KB snippets) 2.6 TB/s.
//   New idx: wave = full 512-px row (8 px/lane), 2 output rows/wave,
//   4 consecutive row-loads (12 KB contiguous per block-channel), vertical
//   register reuse, edge columns via clamp (no divergence, no junk lanes).
//   proj/expand identical to Round 10.

#define CH  32
#define HH  512
#define WW  512
#define EE  64
#define OUT 64
#define PP  10000

#define HW   (HH * WW)        // 262144 = 2^18

typedef float f32x4 __attribute__((ext_vector_type(4)));

__global__ __launch_bounds__(256) void proj_kernel(
    const float* __restrict__ table, const float* __restrict__ pw,
    const float* __restrict__ pb, float* __restrict__ tpT) {
  __shared__ float sW[EE * OUT];          // sW[e*64 + o] = pw[o*64 + e]
  const int t = threadIdx.x;              // 0..255
  for (int i = t; i < EE * OUT; i += 256) {
    int o = i >> 6, e = i & 63;
    sW[e * OUT + o] = pw[i];
  }
  __syncthreads();
  const int o  = t & 63;
  const int pr = t >> 6;                  // 0..3
  const int p0 = blockIdx.x * 16 + pr;    // rows p0, p0+4, p0+8, p0+12
  const float4* r0 = (const float4*)(table + (size_t)(p0     ) * EE);
  const float4* r1 = (const float4*)(table + (size_t)(p0 +  4) * EE);
  const float4* r2 = (const float4*)(table + (size_t)(p0 +  8) * EE);
  const float4* r3 = (const float4*)(table + (size_t)(p0 + 12) * EE);
  float a0 = pb[o], a1 = pb[o], a2 = pb[o], a3 = pb[o];
  float b0 = 0.f,  b1 = 0.f,  b2 = 0.f,  b3 = 0.f;
  #pragma unroll
  for (int e4 = 0; e4 < EE / 4; ++e4) {
    float4 t0 = r0[e4], t1 = r1[e4], t2 = r2[e4], t3 = r3[e4];
    float w0 = sW[(4 * e4 + 0) * OUT + o];
    float w1 = sW[(4 * e4 + 1) * OUT + o];
    float w2 = sW[(4 * e4 + 2) * OUT + o];
    float w3 = sW[(4 * e4 + 3) * OUT + o];
    a0 = fmaf(t0.x, w0, a0); b0 = fmaf(t0.y, w1, b0);
    a0 = fmaf(t0.z, w2, a0); b0 = fmaf(t0.w, w3, b0);
    a1 = fmaf(t1.x, w0, a1); b1 = fmaf(t1.y, w1, b1);
    a1 = fmaf(t1.z, w2, a1); b1 = fmaf(t1.w, w3, b1);
    a2 = fmaf(t2.x, w0, a2); b2 = fmaf(t2.y, w1, b2);
    a2 = fmaf(t2.z, w2, a2); b2 = fmaf(t2.w, w3, b2);
    a3 = fmaf(t3.x, w0, a3); b3 = fmaf(t3.y, w1, b3);
    a3 = fmaf(t3.z, w2, a3); b3 = fmaf(t3.w, w3, b3);
  }
  float* oc = tpT + (size_t)o * PP;
  oc[p0]      = a0 + b0;
  oc[p0 + 4]  = a1 + b1;
  oc[p0 + 8]  = a2 + b2;
  oc[p0 + 12] = a3 + b3;
}

__device__ __forceinline__ int qv(float v) { return (int)(v * 100.0f); }

__device__ __forceinline__ int modp(int h) {
  return (int)((unsigned)(h < 0 ? -h : h) % PP);
}

// block = 128 threads (2 waves). Wave w handles output rows ya=4*bx+2w, ya+1
// across the FULL 512-px row (8 px per lane). Loads rows ya-1..ya+2 (clamped)
// = 4 consecutive rows -> per-channel read is one contiguous 12 KB stream.
__global__ __launch_bounds__(128) void idx_kernel(
    const float* __restrict__ x, unsigned short* __restrict__ idx16) {
  const int t    = threadIdx.x;           // 0..127
  const int lane = t & 63;
  const int w    = t >> 6;                // 0..1
  const int b    = blockIdx.y;
  const int ya   = blockIdx.x * 4 + 2 * w;   // first output row of this wave
  const int x0   = lane * 8;

  const int ru = max(ya - 1, 0);          // row above (clamped)
  const int rd = min(ya + 2, HH - 1);     // row below second output (clamped)
  const size_t o0 = (size_t)ru * WW + x0;
  const size_t o1 = (size_t)ya * WW + x0;
  const size_t o2 = (size_t)(ya + 1) * WW + x0;
  const size_t o3 = (size_t)rd * WW + x0;

  const float* xb = x + (size_t)b * CH * HW;

  int accA[8], accB[8];
  #pragma unroll
  for (int j = 0; j < 8; ++j) { accA[j] = 0; accB[j] = 0; }

  #pragma unroll 2
  for (int c = 0; c < CH; ++c) {
    const float* xc = xb + (size_t)c * HW;
    // 8 independent 16B loads, all issued up front (one 12KB stream/block)
    float4 a0 = *(const float4*)(xc + o0);
    float4 a1 = *(const float4*)(xc + o0 + 4);
    float4 b0 = *(const float4*)(xc + o1);
    float4 b1 = *(const float4*)(xc + o1 + 4);
    float4 c0 = *(const float4*)(xc + o2);
    float4 c1 = *(const float4*)(xc + o2 + 4);
    float4 d0 = *(const float4*)(xc + o3);
    float4 d1 = *(const float4*)(xc + o3 + 4);

    int q0[8] = { qv(a0.x), qv(a0.y), qv(a0.z), qv(a0.w),
                  qv(a1.x), qv(a1.y), qv(a1.z), qv(a1.w) };
    int q1[8] = { qv(b0.x), qv(b0.y), qv(b0.z), qv(b0.w),
                  qv(b1.x), qv(b1.y), qv(b1.z), qv(b1.w) };
    int q2[8] = { qv(c0.x), qv(c0.y), qv(c0.z), qv(c0.w),
                  qv(c1.x), qv(c1.y), qv(c1.z), qv(c1.w) };
    int q3[8] = { qv(d0.x), qv(d0.y), qv(d0.z), qv(d0.w),
                  qv(d1.x), qv(d1.y), qv(d1.z), qv(d1.w) };

    int csA[8], csB[8];
    #pragma unroll
    for (int j = 0; j < 8; ++j) {
      int m = q1[j] + q2[j];
      csA[j] = q0[j] + m;                 // rows ya-1, ya, ya+1
      csB[j] = m + q3[j];                 // rows ya,  ya+1, ya+2
    }

    // neighbor column sums across lanes (full row in one wave)
    int Al = __shfl(csA[7], (lane - 1) & 63, 64);
    int Ar = __shfl(csA[0], (lane + 1) & 63, 64);
    int Bl = __shfl(csB[7], (lane - 1) & 63, 64);
    int Br = __shfl(csB[0], (lane + 1) & 63, 64);
    // image-edge replicate: left neighbor of px0 is px0 itself
    if (lane == 0)  { Al = csA[0]; Bl = csB[0]; }
    if (lane == 63) { Ar = csA[7]; Br = csB[7]; }

    accA[0] += modp(Al + csA[0] + csA[1]);
    accB[0] += modp(Bl + csB[0] + csB[1]);
    #pragma unroll
    for (int j = 1; j < 7; ++j) {
      accA[j] += modp(csA[j - 1] + csA[j] + csA[j + 1]);
      accB[j] += modp(csB[j - 1] + csB[j] + csB[j + 1]);
    }
    accA[7] += modp(csA[6] + csA[7] + Ar);
    accB[7] += modp(csB[6] + csB[7] + Br);
  }

  // mean over 32 channels, exact in f32; trunc of nonneg == >>5
  uint4 pa, pb_;
  pa.x  = (unsigned)(accA[0] >> 5) | ((unsigned)(accA[1] >> 5) << 16);
  pa.y  = (unsigned)(accA[2] >> 5) | ((unsigned)(accA[3] >> 5) << 16);
  pa.z  = (unsigned)(accA[4] >> 5) | ((unsigned)(accA[5] >> 5) << 16);
  pa.w  = (unsigned)(accA[6] >> 5) | ((unsigned)(accA[7] >> 5) << 16);
  pb_.x = (unsigned)(accB[0] >> 5) | ((unsigned)(accB[1] >> 5) << 16);
  pb_.y = (unsigned)(accB[2] >> 5) | ((unsigned)(accB[3] >> 5) << 16);
  pb_.z = (unsigned)(accB[4] >> 5) | ((unsigned)(accB[5] >> 5) << 16);
  pb_.w = (unsigned)(accB[6] >> 5) | ((unsigned)(accB[7] >> 5) << 16);

  unsigned short* orow = idx16 + (size_t)b * HW + (size_t)ya * WW + x0;
  *(uint4*)(orow)      = pa;
  *(uint4*)(orow + WW) = pb_;
}

__global__ __launch_bounds__(256) void expand3_kernel(
    const unsigned short* __restrict__ idx16, const float* __restrict__ tpT,
    float* __restrict__ out) {
  const int t = threadIdx.x;
  const unsigned bid   = blockIdx.x;             // b*2048 + o*32 + chunk
  const int      chunk = bid & 31;               // 32 chunks x 16 rows
  const int      o     = (bid >> 5) & 63;
  const int      b     = bid >> 11;

  const float* col = tpT + (size_t)o * PP;       // hot band <1KB -> L1
  const size_t pixbase = (size_t)chunk * 8192;   // 16 rows
  const unsigned short* ip = idx16 + (size_t)b * HW + pixbase;
  float* op = out + ((size_t)b * OUT + o) * HW + pixbase;

  // batch all 8 idx loads up front (independent), then gather+store pipelined
  uint2 pk0 = *(const uint2*)(ip + 0 * 1024 + t * 4);
  uint2 pk1 = *(const uint2*)(ip + 1 * 1024 + t * 4);
  uint2 pk2 = *(const uint2*)(ip + 2 * 1024 + t * 4);
  uint2 pk3 = *(const uint2*)(ip + 3 * 1024 + t * 4);
  uint2 pk4 = *(const uint2*)(ip + 4 * 1024 + t * 4);
  uint2 pk5 = *(const uint2*)(ip + 5 * 1024 + t * 4);
  uint2 pk6 = *(const uint2*)(ip + 6 * 1024 + t * 4);
  uint2 pk7 = *(const uint2*)(ip + 7 * 1024 + t * 4);

#define EXPAND_ONE(pk, j)                                                  \
  {                                                                        \
    const unsigned i0 = pk.x & 0xFFFFu, i1 = pk.x >> 16;                   \
    const unsigned i2 = pk.y & 0xFFFFu, i3 = pk.y >> 16;                   \
    f32x4 v = { col[i0], col[i1], col[i2], col[i3] };                      \
    __builtin_nontemporal_store(v, (f32x4*)(op + (j) * 1024 + t * 4));     \
  }

  EXPAND_ONE(pk0, 0)
  EXPAND_ONE(pk1, 1)
  EXPAND_ONE(pk2, 2)
  EXPAND_ONE(pk3, 3)
  EXPAND_ONE(pk4, 4)
  EXPAND_ONE(pk5, 5)
  EXPAND_ONE(pk6, 6)
  EXPAND_ONE(pk7, 7)
#undef EXPAND_ONE
}

extern "C" void kernel_launch(void* const* d_in, const int* in_sizes, int n_in,
                              void* d_out, int out_size, void* d_ws, size_t ws_size,
                              hipStream_t stream) {
  const float* x     = (const float*)d_in[0];  // (4,32,512,512)
  const float* table = (const float*)d_in[1];  // (10000,64)
  const float* pw    = (const float*)d_in[2];  // (64,64)
  const float* pb    = (const float*)d_in[3];  // (64,)
  float* out = (float*)d_out;                  // (4,64,512,512)

  const int B = in_sizes[0] / (CH * HW);       // 4

  float* tpT = (float*)d_ws;                                        // 2.56 MB
  unsigned short* idx16 =
      (unsigned short*)((char*)d_ws + (size_t)OUT * PP * 4);        // 2 MB

  proj_kernel<<<PP / 16, 256, 0, stream>>>(table, pw, pb, tpT);

  dim3 grid(HH / 4, B);                        // (128, 4) = 512 blocks
  idx_kernel<<<grid, 128, 0, stream>>>(x, idx16);

  const int nblk = B * OUT * 32;               // 8192 blocks, 16 rows each
  expand3_kernel<<<nblk, 256, 0, stream>>>(idx16, tpT, out);
}